// Round 17
// baseline (79.009 us; speedup 1.0000x reference)
//
#include <hip/hip_runtime.h>
#include <type_traits>

#define BLOCK 256
#define WAVES_PER_BLOCK 4
#define NBLOCKS 4096
#define TILES_PER_WAVE 8
#define QUADS (TILES_PER_WAVE/4)

typedef __fp16 f16;
typedef f16 f16x2 __attribute__((ext_vector_type(2)));
typedef f16 f16x8 __attribute__((ext_vector_type(8)));
typedef float f32x2 __attribute__((ext_vector_type(2)));
typedef float f32x16 __attribute__((ext_vector_type(16)));
typedef unsigned u32x2 __attribute__((ext_vector_type(2)));

__device__ __forceinline__ float ex2(float x){ return __builtin_amdgcn_exp2f(x); }
__device__ __forceinline__ float rcp_(float x){ return __builtin_amdgcn_rcpf(x); }
__device__ __forceinline__ float rsq_(float x){ return __builtin_amdgcn_rsqf(x); }

__device__ __forceinline__ f32x2 mk2(float a, float b){
    f32x2 r; r.x = a; r.y = b; return r;
}

__device__ __forceinline__ unsigned pk2(float a, float b){
    f16x2 h = __builtin_amdgcn_cvt_pkrtz(a, b);
    union { f16x2 h; unsigned u; } cv; cv.h = h; return cv.u;
}

// v_permlane32_swap_b32: r.x = {a_lo31, b_lo31}, r.y = {a_hi31, b_hi31}
__device__ __forceinline__ u32x2 plswap(unsigned a, unsigned b){
    return __builtin_amdgcn_permlane32_swap(a, b, false, false);
}
__device__ __forceinline__ float xhalf_sum(float x){
    union { float f; unsigned u; } cvt; cvt.f = x;
    u32x2 r = plswap(cvt.u, cvt.u);
    union { unsigned u; float f; } lo, hi; lo.u = r.x; hi.u = r.y;
    return lo.f + hi.f;
}

// exact-GELU via A&S 7.1.26 erf (|eps| <= 1.5e-7) — table build only
__device__ __forceinline__ float gelu_ref(float v){
    float av = fabsf(v);
    float e  = ex2(v*v * -0.7213475204444817f);
    float t  = rcp_(fmaf(0.23164190157f, av, 1.0f));
    float p  = fmaf(fmaf(fmaf(fmaf(1.061405429f, t, -1.453152027f), t,
                              1.421413741f), t, -0.284496736f), t, 0.254829592f);
    float pt = p * t;
    float erfabs = fmaf(-pt, e, 1.0f);
    return 0.5f * fmaf(av, erfabs, v);
}

union U8 { f16x8 v; unsigned u[4]; };
union PU { f16x2 v; unsigned u; };

__global__ __launch_bounds__(BLOCK) void nn_kernel(
    const float* __restrict__ feat,
    const float* __restrict__ W0, const float* __restrict__ b0v,
    const float* __restrict__ g0v, const float* __restrict__ be0v,
    const float* __restrict__ W1, const float* __restrict__ b1v,
    const float* __restrict__ g1v, const float* __restrict__ be1v,
    const float* __restrict__ W2, const float* __restrict__ b2v,
    const float* __restrict__ g2v, const float* __restrict__ be2v,
    const float* __restrict__ Wo, const float* __restrict__ bov,
    float* __restrict__ out)
{
    // padded GELU table: 1024 bins, one f16 per 4-byte slot (bank-stride 1)
    __shared__ __align__(16) f16   tabH[2048];
    __shared__ __align__(16) float cb[3][16];
    __shared__ __align__(16) float cg[3][16];
    __shared__ __align__(16) float cbe[3][16];
    __shared__ __align__(16) float cbo[4];

    const int tid = threadIdx.x;
    if (tid < 16){
        cb[0][tid]  = b0v[tid];  cb[1][tid]  = b1v[tid];  cb[2][tid]  = b2v[tid];
        cg[0][tid]  = g0v[tid];  cg[1][tid]  = g1v[tid];  cg[2][tid]  = g2v[tid];
        cbe[0][tid] = be0v[tid]; cbe[1][tid] = be1v[tid]; cbe[2][tid] = be2v[tid];
    }
    if (tid < 4) cbo[tid] = bov[tid];
    for (int i = tid; i < 1024; i += BLOCK){
        float v = (float)(i - 512) * (1.0f/128.0f) + (0.5f/128.0f);
        tabH[2*i] = (f16)gelu_ref(v);
    }
    __syncthreads();

    const int lane = tid & 63;
    const int wv   = tid >> 6;
    const int gg   = lane >> 5;      // k-group / n-group selector
    const int c    = lane & 31;      // A row (neuron) / B col (data row)

    // ---- weight A-fragments: A[n][k] = W[k][n], lane: a[j]=A[c][gg*8+j] ----
    // layer-0: bias folded into k=8 (gg==1, j==0): A[n][8] = b0[n]; k=9..15 = 0
    U8 aW0, aW1, aW2, aWo;
    {
        float w[8];
        #pragma unroll
        for (int j=0;j<8;++j){
            if (gg==0) w[j] = (c<16) ? W0[j*16 + c] : 0.f;
            else       w[j] = (j==0 && c<16) ? b0v[c] : 0.f;
        }
        aW0.u[0]=pk2(w[0],w[1]); aW0.u[1]=pk2(w[2],w[3]);
        aW0.u[2]=pk2(w[4],w[5]); aW0.u[3]=pk2(w[6],w[7]);
        #pragma unroll
        for (int j=0;j<8;++j) w[j] = (c<16) ? W1[(gg*8+j)*16 + c] : 0.f;
        aW1.u[0]=pk2(w[0],w[1]); aW1.u[1]=pk2(w[2],w[3]);
        aW1.u[2]=pk2(w[4],w[5]); aW1.u[3]=pk2(w[6],w[7]);
        #pragma unroll
        for (int j=0;j<8;++j) w[j] = (c<16) ? W2[(gg*8+j)*16 + c] : 0.f;
        aW2.u[0]=pk2(w[0],w[1]); aW2.u[1]=pk2(w[2],w[3]);
        aW2.u[2]=pk2(w[4],w[5]); aW2.u[3]=pk2(w[6],w[7]);
        // output split: A rows 0,1 <- Wo cols 0,1 ; A rows 4,5 <- Wo cols 2,3
        const int eidx = (c < 2) ? c : ((c == 4 || c == 5) ? (c - 2) : -1);
        #pragma unroll
        for (int j=0;j<8;++j) w[j] = (eidx >= 0) ? Wo[(gg*8+j)*4 + eidx] : 0.f;
        aWo.u[0]=pk2(w[0],w[1]); aWo.u[1]=pk2(w[2],w[3]);
        aWo.u[2]=pk2(w[4],w[5]); aWo.u[3]=pk2(w[6],w[7]);
    }

    // ---- wave-uniform "gamma==1 && beta==0" fast-path flag ----
    bool okl = true;
    if (lane < 16){
        #pragma unroll
        for (int l=0;l<3;++l)
            okl = okl && (cg[l][lane]==1.0f) && (cbe[l][lane]==0.0f);
    }
    const bool triv = (__ballot(okl) == 0xFFFFFFFFFFFFFFFFull);

    // ---- per-lane bias pairs for layers 1,2 (packed f32) ----
    const int n0 = 4*gg, n1 = 8 + 4*gg;
    const float4 b1q0 = *(const float4*)&cb[1][n0], b1q1 = *(const float4*)&cb[1][n1];
    const float4 b2q0 = *(const float4*)&cb[2][n0], b2q1 = *(const float4*)&cb[2][n1];
    const f32x2 b1p0 = mk2(b1q0.x,b1q0.y), b1p1 = mk2(b1q0.z,b1q0.w);
    const f32x2 b1p2 = mk2(b1q1.x,b1q1.y), b1p3 = mk2(b1q1.z,b1q1.w);
    const f32x2 b2p0 = mk2(b2q0.x,b2q0.y), b2p1 = mk2(b2q0.z,b2q0.w);
    const f32x2 b2p2 = mk2(b2q1.x,b2q1.y), b2p3 = mk2(b2q1.z,b2q1.w);
    const float K = 2.8853900817779268f;   // 2/ln2
    const f32x2 K2   = mk2(K, K);
    const f32x2 bo22 = mk2(cbo[2*gg]*K, cbo[2*gg+1]*K);

    f32x16 zC;
    #pragma unroll
    for (int i=0;i<16;++i) zC[i]=0.f;

    const long gw = (long)blockIdx.x * WAVES_PER_BLOCK + wv;
    const long rowbase = gw * (TILES_PER_WAVE*32L);
    const char* fb = (const char*)feat + (rowbase + c) * 32L;   // same addr both halves
    char*       ob = (char*)out        + (rowbase + c) * 16L + gg*8;

    auto body = [&](auto TRIVC){
        constexpr bool TRIV = decltype(TRIVC)::value;

        // LN + GELU(padded f16 table) + pack -> next-layer B fragment
        auto lnact = [&](f32x2 h01, f32x2 h23, f32x2 h45, f32x2 h67, int l) -> U8 {
            f32x2 sp = (h01 + h23) + (h45 + h67);              // 3 pk_add
            float s  = sp.x + sp.y;
            f32x2 q  = h01 * h01;                              // pk_mul
            q = __builtin_elementwise_fma(h23, h23, q);        // pk_fma
            q = __builtin_elementwise_fma(h45, h45, q);
            q = __builtin_elementwise_fma(h67, h67, q);
            float s2 = q.x + q.y;
            s  = xhalf_sum(s);
            s2 = xhalf_sum(s2);
            const float mu  = s * 0.0625f;
            const float var = fmaf(-mu, mu, s2 * 0.0625f);
            const float rs  = rsq_(var + 1e-5f);

            PU p0, p1, p2, p3;
            if constexpr (TRIV){
                const float Ri = rs * 128.f;
                const float Ni = fmaf(-mu, Ri, 512.f);
                const f32x2 R2 = mk2(Ri, Ri), N2 = mk2(Ni, Ni);
                f32x2 i01 = __builtin_elementwise_fma(h01, R2, N2);
                f32x2 i23 = __builtin_elementwise_fma(h23, R2, N2);
                f32x2 i45 = __builtin_elementwise_fma(h45, R2, N2);
                f32x2 i67 = __builtin_elementwise_fma(h67, R2, N2);
                // idx guaranteed in [16, 1008]; padded slot = 2*idx
                p0.v.x = tabH[((int)i01.x)*2]; p0.v.y = tabH[((int)i01.y)*2];
                p1.v.x = tabH[((int)i23.x)*2]; p1.v.y = tabH[((int)i23.y)*2];
                p2.v.x = tabH[((int)i45.x)*2]; p2.v.y = tabH[((int)i45.y)*2];
                p3.v.x = tabH[((int)i67.x)*2]; p3.v.y = tabH[((int)i67.y)*2];
            } else {
                const float nm = -mu * rs;
                const float4 gq0 = *(const float4*)&cg[l][n0];
                const float4 gq1 = *(const float4*)&cg[l][n1];
                const float4 eq0 = *(const float4*)&cbe[l][n0];
                const float4 eq1 = *(const float4*)&cbe[l][n1];
                const float hv[8] = {h01.x,h01.y,h23.x,h23.y,h45.x,h45.y,h67.x,h67.y};
                const float ga[8] = {gq0.x,gq0.y,gq0.z,gq0.w, gq1.x,gq1.y,gq1.z,gq1.w};
                const float ba[8] = {eq0.x,eq0.y,eq0.z,eq0.w, eq1.x,eq1.y,eq1.z,eq1.w};
                float xf[8];
                #pragma unroll
                for (int i=0;i<8;++i){
                    float t  = fmaf(hv[i], rs, nm);
                    t = fmaf(t, ga[i], ba[i]);
                    xf[i] = fminf(fmaxf(fmaf(t, 128.f, 512.f), 0.f), 1023.f);
                }
                p0.v.x = tabH[((int)xf[0])*2]; p0.v.y = tabH[((int)xf[1])*2];
                p1.v.x = tabH[((int)xf[2])*2]; p1.v.y = tabH[((int)xf[3])*2];
                p2.v.x = tabH[((int)xf[4])*2]; p2.v.y = tabH[((int)xf[5])*2];
                p3.v.x = tabH[((int)xf[6])*2]; p3.v.y = tabH[((int)xf[7])*2];
            }
            u32x2 e0 = plswap(p0.u, p2.u);
            u32x2 e1 = plswap(p1.u, p3.u);
            U8 F;
            F.u[0] = e0.x; F.u[1] = e1.x; F.u[2] = e0.y; F.u[3] = e1.y;
            return F;
        };

        // ---- prefetch tiles 0,1 of quad 0 ----
        float4 p0a = *(const float4*)(fb +    0), p0b = *(const float4*)(fb +   16);
        float4 p1a = *(const float4*)(fb + 1024), p1b = *(const float4*)(fb + 1040);

        #pragma unroll 1
        for (int q = 0; q < QUADS; ++q){
            const char* fq = fb + q*4096L;

            // ---- tiles 2,3 of this quad load now ----
            float4 t2a = *(const float4*)(fq + 2048), t2b = *(const float4*)(fq + 2064);
            float4 t3a = *(const float4*)(fq + 3072), t3b = *(const float4*)(fq + 3088);

            // ---- layer-0 B fragments (tiles 0,1 from prefetch regs) ----
            U8 B0, B1, B2, B3;
            B0.u[0]=pk2(p0a.x,p0a.y); B0.u[1]=pk2(p0a.z,p0a.w);
            B0.u[2]=pk2(p0b.x,p0b.y); B0.u[3]=pk2(p0b.z,p0b.w);
            B1.u[0]=pk2(p1a.x,p1a.y); B1.u[1]=pk2(p1a.z,p1a.w);
            B1.u[2]=pk2(p1b.x,p1b.y); B1.u[3]=pk2(p1b.z,p1b.w);
            B2.u[0]=pk2(t2a.x,t2a.y); B2.u[1]=pk2(t2a.z,t2a.w);
            B2.u[2]=pk2(t2b.x,t2b.y); B2.u[3]=pk2(t2b.z,t2b.w);
            B3.u[0]=pk2(t3a.x,t3a.y); B3.u[1]=pk2(t3a.z,t3a.w);
            B3.u[2]=pk2(t3b.x,t3b.y); B3.u[3]=pk2(t3b.z,t3b.w);
            if (gg){
                B0.u[0]=0x00003C00u; B1.u[0]=0x00003C00u;
                B2.u[0]=0x00003C00u; B3.u[0]=0x00003C00u;
            }

            // ---- issue next quad's tiles 0,1 now (hide HBM under compute) ----
            {
                const char* pn = fb + ((q+1 < QUADS) ? (q+1) : q)*4096L;
                p0a = *(const float4*)(pn +    0); p0b = *(const float4*)(pn +   16);
                p1a = *(const float4*)(pn + 1024); p1b = *(const float4*)(pn + 1040);
            }

            // ---- layer 0 ----
            f32x16 h0 = __builtin_amdgcn_mfma_f32_32x32x16_f16(aW0.v, B0.v, zC, 0,0,0);
            f32x16 h1 = __builtin_amdgcn_mfma_f32_32x32x16_f16(aW0.v, B1.v, zC, 0,0,0);
            f32x16 h2 = __builtin_amdgcn_mfma_f32_32x32x16_f16(aW0.v, B2.v, zC, 0,0,0);
            f32x16 h3 = __builtin_amdgcn_mfma_f32_32x32x16_f16(aW0.v, B3.v, zC, 0,0,0);

            U8 F0 = lnact(mk2(h0[0],h0[1]), mk2(h0[2],h0[3]), mk2(h0[4],h0[5]), mk2(h0[6],h0[7]), 0);
            U8 F1 = lnact(mk2(h1[0],h1[1]), mk2(h1[2],h1[3]), mk2(h1[4],h1[5]), mk2(h1[6],h1[7]), 0);
            U8 F2 = lnact(mk2(h2[0],h2[1]), mk2(h2[2],h2[3]), mk2(h2[4],h2[5]), mk2(h2[6],h2[7]), 0);
            U8 F3 = lnact(mk2(h3[0],h3[1]), mk2(h3[2],h3[3]), mk2(h3[4],h3[5]), mk2(h3[6],h3[7]), 0);

            // ---- layer 1 (bias added packed) ----
            h0 = __builtin_amdgcn_mfma_f32_32x32x16_f16(aW1.v, F0.v, zC, 0,0,0);
            h1 = __builtin_amdgcn_mfma_f32_32x32x16_f16(aW1.v, F1.v, zC, 0,0,0);
            h2 = __builtin_amdgcn_mfma_f32_32x32x16_f16(aW1.v, F2.v, zC, 0,0,0);
            h3 = __builtin_amdgcn_mfma_f32_32x32x16_f16(aW1.v, F3.v, zC, 0,0,0);
            F0 = lnact(mk2(h0[0],h0[1])+b1p0, mk2(h0[2],h0[3])+b1p1,
                       mk2(h0[4],h0[5])+b1p2, mk2(h0[6],h0[7])+b1p3, 1);
            F1 = lnact(mk2(h1[0],h1[1])+b1p0, mk2(h1[2],h1[3])+b1p1,
                       mk2(h1[4],h1[5])+b1p2, mk2(h1[6],h1[7])+b1p3, 1);
            F2 = lnact(mk2(h2[0],h2[1])+b1p0, mk2(h2[2],h2[3])+b1p1,
                       mk2(h2[4],h2[5])+b1p2, mk2(h2[6],h2[7])+b1p3, 1);
            F3 = lnact(mk2(h3[0],h3[1])+b1p0, mk2(h3[2],h3[3])+b1p1,
                       mk2(h3[4],h3[5])+b1p2, mk2(h3[6],h3[7])+b1p3, 1);

            // ---- layer 2 ----
            h0 = __builtin_amdgcn_mfma_f32_32x32x16_f16(aW2.v, F0.v, zC, 0,0,0);
            h1 = __builtin_amdgcn_mfma_f32_32x32x16_f16(aW2.v, F1.v, zC, 0,0,0);
            h2 = __builtin_amdgcn_mfma_f32_32x32x16_f16(aW2.v, F2.v, zC, 0,0,0);
            h3 = __builtin_amdgcn_mfma_f32_32x32x16_f16(aW2.v, F3.v, zC, 0,0,0);
            F0 = lnact(mk2(h0[0],h0[1])+b2p0, mk2(h0[2],h0[3])+b2p1,
                       mk2(h0[4],h0[5])+b2p2, mk2(h0[6],h0[7])+b2p3, 2);
            F1 = lnact(mk2(h1[0],h1[1])+b2p0, mk2(h1[2],h1[3])+b2p1,
                       mk2(h1[4],h1[5])+b2p2, mk2(h1[6],h1[7])+b2p3, 2);
            F2 = lnact(mk2(h2[0],h2[1])+b2p0, mk2(h2[2],h2[3])+b2p1,
                       mk2(h2[4],h2[5])+b2p2, mk2(h2[6],h2[7])+b2p3, 2);
            F3 = lnact(mk2(h3[0],h3[1])+b2p0, mk2(h3[2],h3[3])+b2p1,
                       mk2(h3[4],h3[5])+b2p2, mk2(h3[6],h3[7])+b2p3, 2);

            // ---- output layer (split: gg0 -> e0,e1 ; gg1 -> e2,e3) ----
            h0 = __builtin_amdgcn_mfma_f32_32x32x16_f16(aWo.v, F0.v, zC, 0,0,0);
            h1 = __builtin_amdgcn_mfma_f32_32x32x16_f16(aWo.v, F1.v, zC, 0,0,0);
            h2 = __builtin_amdgcn_mfma_f32_32x32x16_f16(aWo.v, F2.v, zC, 0,0,0);
            h3 = __builtin_amdgcn_mfma_f32_32x32x16_f16(aWo.v, F3.v, zC, 0,0,0);

            // f_a = 2 - 2/(exp(z*K + bo*K)+1), packed pre-scale then scalar trans
            f32x2 z0 = __builtin_elementwise_fma(mk2(h0[0],h0[1]), K2, bo22);
            f32x2 z1 = __builtin_elementwise_fma(mk2(h1[0],h1[1]), K2, bo22);
            f32x2 z2 = __builtin_elementwise_fma(mk2(h2[0],h2[1]), K2, bo22);
            f32x2 z3 = __builtin_elementwise_fma(mk2(h3[0],h3[1]), K2, bo22);
            float2 r0, r1, r2, r3;
            r0.x = fmaf(-2.0f, rcp_(ex2(z0.x)+1.0f), 2.0f);
            r0.y = fmaf(-2.0f, rcp_(ex2(z0.y)+1.0f), 2.0f);
            r1.x = fmaf(-2.0f, rcp_(ex2(z1.x)+1.0f), 2.0f);
            r1.y = fmaf(-2.0f, rcp_(ex2(z1.y)+1.0f), 2.0f);
            r2.x = fmaf(-2.0f, rcp_(ex2(z2.x)+1.0f), 2.0f);
            r2.y = fmaf(-2.0f, rcp_(ex2(z2.y)+1.0f), 2.0f);
            r3.x = fmaf(-2.0f, rcp_(ex2(z3.x)+1.0f), 2.0f);
            r3.y = fmaf(-2.0f, rcp_(ex2(z3.y)+1.0f), 2.0f);
            *(float2*)(ob + q*2048L       ) = r0;
            *(float2*)(ob + q*2048L +  512) = r1;
            *(float2*)(ob + q*2048L + 1024) = r2;
            *(float2*)(ob + q*2048L + 1536) = r3;
        }
    };

    if (triv) body(std::integral_constant<bool,true>{});
    else      body(std::integral_constant<bool,false>{});
}

extern "C" void kernel_launch(void* const* d_in, const int* in_sizes, int n_in,
                              void* d_out, int out_size, void* d_ws, size_t ws_size,
                              hipStream_t stream) {
    const float* feat = (const float*)d_in[0];
    const float* W0  = (const float*)d_in[1];
    const float* b0  = (const float*)d_in[2];
    const float* g0  = (const float*)d_in[3];
    const float* be0 = (const float*)d_in[4];
    const float* W1  = (const float*)d_in[5];
    const float* b1  = (const float*)d_in[6];
    const float* g1  = (const float*)d_in[7];
    const float* be1 = (const float*)d_in[8];
    const float* W2  = (const float*)d_in[9];
    const float* b2  = (const float*)d_in[10];
    const float* g2  = (const float*)d_in[11];
    const float* be2 = (const float*)d_in[12];
    const float* Wo  = (const float*)d_in[13];
    const float* bo  = (const float*)d_in[14];
    float* out = (float*)d_out;

    hipLaunchKernelGGL(nn_kernel, dim3(NBLOCKS), dim3(BLOCK), 0, stream,
                       feat, W0, b0, g0, be0, W1, b1, g1, be1,
                       W2, b2, g2, be2, Wo, bo, out);
}

// Round 18
// 73.550 us; speedup vs baseline: 1.0742x; 1.0742x over previous
//
#include <hip/hip_runtime.h>
#include <type_traits>

#define BLOCK 256
#define WAVES_PER_BLOCK 4
#define NBLOCKS 2048
#define TILES_PER_WAVE 16
#define QUADS (TILES_PER_WAVE/4)

typedef __fp16 f16;
typedef f16 f16x2 __attribute__((ext_vector_type(2)));
typedef f16 f16x8 __attribute__((ext_vector_type(8)));
typedef float f32x2 __attribute__((ext_vector_type(2)));
typedef float f32x16 __attribute__((ext_vector_type(16)));
typedef unsigned u32x2 __attribute__((ext_vector_type(2)));

__device__ __forceinline__ float ex2(float x){ return __builtin_amdgcn_exp2f(x); }
__device__ __forceinline__ float rcp_(float x){ return __builtin_amdgcn_rcpf(x); }
__device__ __forceinline__ float rsq_(float x){ return __builtin_amdgcn_rsqf(x); }

__device__ __forceinline__ f32x2 mk2(float a, float b){
    f32x2 r; r.x = a; r.y = b; return r;
}

__device__ __forceinline__ unsigned pk2(float a, float b){
    f16x2 h = __builtin_amdgcn_cvt_pkrtz(a, b);
    union { f16x2 h; unsigned u; } cv; cv.h = h; return cv.u;
}

// v_permlane32_swap_b32: r.x = {a_lo31, b_lo31}, r.y = {a_hi31, b_hi31}
__device__ __forceinline__ u32x2 plswap(unsigned a, unsigned b){
    return __builtin_amdgcn_permlane32_swap(a, b, false, false);
}
__device__ __forceinline__ float xhalf_sum(float x){
    union { float f; unsigned u; } cvt; cvt.f = x;
    u32x2 r = plswap(cvt.u, cvt.u);
    union { unsigned u; float f; } lo, hi; lo.u = r.x; hi.u = r.y;
    return lo.f + hi.f;
}

// exact-GELU via A&S 7.1.26 erf (|eps| <= 1.5e-7) — table build only
__device__ __forceinline__ float gelu_ref(float v){
    float av = fabsf(v);
    float e  = ex2(v*v * -0.7213475204444817f);
    float t  = rcp_(fmaf(0.23164190157f, av, 1.0f));
    float p  = fmaf(fmaf(fmaf(fmaf(1.061405429f, t, -1.453152027f), t,
                              1.421413741f), t, -0.284496736f), t, 0.254829592f);
    float pt = p * t;
    float erfabs = fmaf(-pt, e, 1.0f);
    return 0.5f * fmaf(av, erfabs, v);
}

union U8 { f16x8 v; unsigned u[4]; };
union PU { f16x2 v; unsigned u; };

__global__ __launch_bounds__(BLOCK) void nn_kernel(
    const float* __restrict__ feat,
    const float* __restrict__ W0, const float* __restrict__ b0v,
    const float* __restrict__ g0v, const float* __restrict__ be0v,
    const float* __restrict__ W1, const float* __restrict__ b1v,
    const float* __restrict__ g1v, const float* __restrict__ be1v,
    const float* __restrict__ W2, const float* __restrict__ b2v,
    const float* __restrict__ g2v, const float* __restrict__ be2v,
    const float* __restrict__ Wo, const float* __restrict__ bov,
    float* __restrict__ out)
{
    __shared__ __align__(16) f16   tabH[1024];   // f16 GELU table, step 1/128 (2KB)
    __shared__ __align__(16) float cb[3][16];
    __shared__ __align__(16) float cg[3][16];
    __shared__ __align__(16) float cbe[3][16];
    __shared__ __align__(16) float cbo[4];

    const int tid = threadIdx.x;
    if (tid < 16){
        cb[0][tid]  = b0v[tid];  cb[1][tid]  = b1v[tid];  cb[2][tid]  = b2v[tid];
        cg[0][tid]  = g0v[tid];  cg[1][tid]  = g1v[tid];  cg[2][tid]  = g2v[tid];
        cbe[0][tid] = be0v[tid]; cbe[1][tid] = be1v[tid]; cbe[2][tid] = be2v[tid];
    }
    if (tid < 4) cbo[tid] = bov[tid];
    for (int i = tid; i < 1024; i += BLOCK){
        float v = (float)(i - 512) * (1.0f/128.0f) + (0.5f/128.0f);
        tabH[i] = (f16)gelu_ref(v);
    }
    __syncthreads();

    const int lane = tid & 63;
    const int wv   = tid >> 6;
    const int gg   = lane >> 5;      // k-group / n-group selector
    const int c    = lane & 31;      // A row (neuron) / B col (data row)

    // ---- weight A-fragments: A[n][k] = W[k][n], lane: a[j]=A[c][gg*8+j] ----
    // layer-0: bias folded into k=8 (gg==1, j==0): A[n][8] = b0[n]; k=9..15 = 0
    U8 aW0, aW1, aW2, aWo;
    {
        float w[8];
        #pragma unroll
        for (int j=0;j<8;++j){
            if (gg==0) w[j] = (c<16) ? W0[j*16 + c] : 0.f;
            else       w[j] = (j==0 && c<16) ? b0v[c] : 0.f;
        }
        aW0.u[0]=pk2(w[0],w[1]); aW0.u[1]=pk2(w[2],w[3]);
        aW0.u[2]=pk2(w[4],w[5]); aW0.u[3]=pk2(w[6],w[7]);
        #pragma unroll
        for (int j=0;j<8;++j) w[j] = (c<16) ? W1[(gg*8+j)*16 + c] : 0.f;
        aW1.u[0]=pk2(w[0],w[1]); aW1.u[1]=pk2(w[2],w[3]);
        aW1.u[2]=pk2(w[4],w[5]); aW1.u[3]=pk2(w[6],w[7]);
        #pragma unroll
        for (int j=0;j<8;++j) w[j] = (c<16) ? W2[(gg*8+j)*16 + c] : 0.f;
        aW2.u[0]=pk2(w[0],w[1]); aW2.u[1]=pk2(w[2],w[3]);
        aW2.u[2]=pk2(w[4],w[5]); aW2.u[3]=pk2(w[6],w[7]);
        // output split: A rows 0,1 <- Wo cols 0,1 ; A rows 4,5 <- Wo cols 2,3
        const int eidx = (c < 2) ? c : ((c == 4 || c == 5) ? (c - 2) : -1);
        #pragma unroll
        for (int j=0;j<8;++j) w[j] = (eidx >= 0) ? Wo[(gg*8+j)*4 + eidx] : 0.f;
        aWo.u[0]=pk2(w[0],w[1]); aWo.u[1]=pk2(w[2],w[3]);
        aWo.u[2]=pk2(w[4],w[5]); aWo.u[3]=pk2(w[6],w[7]);
    }

    // ---- wave-uniform "gamma==1 && beta==0" fast-path flag ----
    bool okl = true;
    if (lane < 16){
        #pragma unroll
        for (int l=0;l<3;++l)
            okl = okl && (cg[l][lane]==1.0f) && (cbe[l][lane]==0.0f);
    }
    const bool triv = (__ballot(okl) == 0xFFFFFFFFFFFFFFFFull);

    // ---- per-lane bias pairs for layers 1,2 (packed f32) ----
    const int n0 = 4*gg, n1 = 8 + 4*gg;
    const float4 b1q0 = *(const float4*)&cb[1][n0], b1q1 = *(const float4*)&cb[1][n1];
    const float4 b2q0 = *(const float4*)&cb[2][n0], b2q1 = *(const float4*)&cb[2][n1];
    const f32x2 b1p0 = mk2(b1q0.x,b1q0.y), b1p1 = mk2(b1q0.z,b1q0.w);
    const f32x2 b1p2 = mk2(b1q1.x,b1q1.y), b1p3 = mk2(b1q1.z,b1q1.w);
    const f32x2 b2p0 = mk2(b2q0.x,b2q0.y), b2p1 = mk2(b2q0.z,b2q0.w);
    const f32x2 b2p2 = mk2(b2q1.x,b2q1.y), b2p3 = mk2(b2q1.z,b2q1.w);
    const float K = 2.8853900817779268f;   // 2/ln2
    const f32x2 K2   = mk2(K, K);
    const f32x2 bo22 = mk2(cbo[2*gg]*K, cbo[2*gg+1]*K);

    f32x16 zC;
    #pragma unroll
    for (int i=0;i<16;++i) zC[i]=0.f;

    const long gw = (long)blockIdx.x * WAVES_PER_BLOCK + wv;
    const long rowbase = gw * (TILES_PER_WAVE*32L);
    const char* fb = (const char*)feat + (rowbase + c) * 32L;   // same addr both halves
    char*       ob = (char*)out        + (rowbase + c) * 16L + gg*8;

    auto body = [&](auto TRIVC){
        constexpr bool TRIV = decltype(TRIVC)::value;

        // LN + GELU(f16 table) + pack -> next-layer B fragment
        auto lnact = [&](f32x2 h01, f32x2 h23, f32x2 h45, f32x2 h67, int l) -> U8 {
            f32x2 sp = (h01 + h23) + (h45 + h67);              // 3 pk_add
            float s  = sp.x + sp.y;
            f32x2 q  = h01 * h01;                              // pk_mul
            q = __builtin_elementwise_fma(h23, h23, q);        // pk_fma
            q = __builtin_elementwise_fma(h45, h45, q);
            q = __builtin_elementwise_fma(h67, h67, q);
            float s2 = q.x + q.y;
            s  = xhalf_sum(s);
            s2 = xhalf_sum(s2);
            const float mu  = s * 0.0625f;
            const float var = fmaf(-mu, mu, s2 * 0.0625f);
            const float rs  = rsq_(var + 1e-5f);

            PU p0, p1, p2, p3;
            if constexpr (TRIV){
                const float Ri = rs * 128.f;
                const float Ni = fmaf(-mu, Ri, 512.f);
                const f32x2 R2 = mk2(Ri, Ri), N2 = mk2(Ni, Ni);
                f32x2 i01 = __builtin_elementwise_fma(h01, R2, N2);
                f32x2 i23 = __builtin_elementwise_fma(h23, R2, N2);
                f32x2 i45 = __builtin_elementwise_fma(h45, R2, N2);
                f32x2 i67 = __builtin_elementwise_fma(h67, R2, N2);
                // idx guaranteed in [16, 1008]
                p0.v.x = tabH[(int)i01.x]; p0.v.y = tabH[(int)i01.y];
                p1.v.x = tabH[(int)i23.x]; p1.v.y = tabH[(int)i23.y];
                p2.v.x = tabH[(int)i45.x]; p2.v.y = tabH[(int)i45.y];
                p3.v.x = tabH[(int)i67.x]; p3.v.y = tabH[(int)i67.y];
            } else {
                const float nm = -mu * rs;
                const float4 gq0 = *(const float4*)&cg[l][n0];
                const float4 gq1 = *(const float4*)&cg[l][n1];
                const float4 eq0 = *(const float4*)&cbe[l][n0];
                const float4 eq1 = *(const float4*)&cbe[l][n1];
                const float hv[8] = {h01.x,h01.y,h23.x,h23.y,h45.x,h45.y,h67.x,h67.y};
                const float ga[8] = {gq0.x,gq0.y,gq0.z,gq0.w, gq1.x,gq1.y,gq1.z,gq1.w};
                const float ba[8] = {eq0.x,eq0.y,eq0.z,eq0.w, eq1.x,eq1.y,eq1.z,eq1.w};
                float xf[8];
                #pragma unroll
                for (int i=0;i<8;++i){
                    float t  = fmaf(hv[i], rs, nm);
                    t = fmaf(t, ga[i], ba[i]);
                    xf[i] = fminf(fmaxf(fmaf(t, 128.f, 512.f), 0.f), 1023.f);
                }
                p0.v.x = tabH[(int)xf[0]]; p0.v.y = tabH[(int)xf[1]];
                p1.v.x = tabH[(int)xf[2]]; p1.v.y = tabH[(int)xf[3]];
                p2.v.x = tabH[(int)xf[4]]; p2.v.y = tabH[(int)xf[5]];
                p3.v.x = tabH[(int)xf[6]]; p3.v.y = tabH[(int)xf[7]];
            }
            u32x2 e0 = plswap(p0.u, p2.u);
            u32x2 e1 = plswap(p1.u, p3.u);
            U8 F;
            F.u[0] = e0.x; F.u[1] = e1.x; F.u[2] = e0.y; F.u[3] = e1.y;
            return F;
        };

        // ---- prefetch tiles 0,1 of quad 0 ----
        float4 p0a = *(const float4*)(fb +    0), p0b = *(const float4*)(fb +   16);
        float4 p1a = *(const float4*)(fb + 1024), p1b = *(const float4*)(fb + 1040);

        #pragma unroll 1
        for (int q = 0; q < QUADS; ++q){
            const char* fq = fb + q*4096L;

            // ---- tiles 2,3 of this quad load now ----
            float4 t2a = *(const float4*)(fq + 2048), t2b = *(const float4*)(fq + 2064);
            float4 t3a = *(const float4*)(fq + 3072), t3b = *(const float4*)(fq + 3088);

            // ---- layer-0 B fragments (tiles 0,1 from prefetch regs) ----
            U8 B0, B1, B2, B3;
            B0.u[0]=pk2(p0a.x,p0a.y); B0.u[1]=pk2(p0a.z,p0a.w);
            B0.u[2]=pk2(p0b.x,p0b.y); B0.u[3]=pk2(p0b.z,p0b.w);
            B1.u[0]=pk2(p1a.x,p1a.y); B1.u[1]=pk2(p1a.z,p1a.w);
            B1.u[2]=pk2(p1b.x,p1b.y); B1.u[3]=pk2(p1b.z,p1b.w);
            B2.u[0]=pk2(t2a.x,t2a.y); B2.u[1]=pk2(t2a.z,t2a.w);
            B2.u[2]=pk2(t2b.x,t2b.y); B2.u[3]=pk2(t2b.z,t2b.w);
            B3.u[0]=pk2(t3a.x,t3a.y); B3.u[1]=pk2(t3a.z,t3a.w);
            B3.u[2]=pk2(t3b.x,t3b.y); B3.u[3]=pk2(t3b.z,t3b.w);
            if (gg){
                B0.u[0]=0x00003C00u; B1.u[0]=0x00003C00u;
                B2.u[0]=0x00003C00u; B3.u[0]=0x00003C00u;
            }

            // ---- issue next quad's tiles 0,1 now (hide HBM under compute) ----
            {
                const char* pn = fb + ((q+1 < QUADS) ? (q+1) : q)*4096L;
                p0a = *(const float4*)(pn +    0); p0b = *(const float4*)(pn +   16);
                p1a = *(const float4*)(pn + 1024); p1b = *(const float4*)(pn + 1040);
            }

            // ---- layer 0 ----
            f32x16 h0 = __builtin_amdgcn_mfma_f32_32x32x16_f16(aW0.v, B0.v, zC, 0,0,0);
            f32x16 h1 = __builtin_amdgcn_mfma_f32_32x32x16_f16(aW0.v, B1.v, zC, 0,0,0);
            f32x16 h2 = __builtin_amdgcn_mfma_f32_32x32x16_f16(aW0.v, B2.v, zC, 0,0,0);
            f32x16 h3 = __builtin_amdgcn_mfma_f32_32x32x16_f16(aW0.v, B3.v, zC, 0,0,0);

            U8 F0 = lnact(mk2(h0[0],h0[1]), mk2(h0[2],h0[3]), mk2(h0[4],h0[5]), mk2(h0[6],h0[7]), 0);
            U8 F1 = lnact(mk2(h1[0],h1[1]), mk2(h1[2],h1[3]), mk2(h1[4],h1[5]), mk2(h1[6],h1[7]), 0);
            U8 F2 = lnact(mk2(h2[0],h2[1]), mk2(h2[2],h2[3]), mk2(h2[4],h2[5]), mk2(h2[6],h2[7]), 0);
            U8 F3 = lnact(mk2(h3[0],h3[1]), mk2(h3[2],h3[3]), mk2(h3[4],h3[5]), mk2(h3[6],h3[7]), 0);

            // ---- layer 1 (bias added packed) ----
            h0 = __builtin_amdgcn_mfma_f32_32x32x16_f16(aW1.v, F0.v, zC, 0,0,0);
            h1 = __builtin_amdgcn_mfma_f32_32x32x16_f16(aW1.v, F1.v, zC, 0,0,0);
            h2 = __builtin_amdgcn_mfma_f32_32x32x16_f16(aW1.v, F2.v, zC, 0,0,0);
            h3 = __builtin_amdgcn_mfma_f32_32x32x16_f16(aW1.v, F3.v, zC, 0,0,0);
            F0 = lnact(mk2(h0[0],h0[1])+b1p0, mk2(h0[2],h0[3])+b1p1,
                       mk2(h0[4],h0[5])+b1p2, mk2(h0[6],h0[7])+b1p3, 1);
            F1 = lnact(mk2(h1[0],h1[1])+b1p0, mk2(h1[2],h1[3])+b1p1,
                       mk2(h1[4],h1[5])+b1p2, mk2(h1[6],h1[7])+b1p3, 1);
            F2 = lnact(mk2(h2[0],h2[1])+b1p0, mk2(h2[2],h2[3])+b1p1,
                       mk2(h2[4],h2[5])+b1p2, mk2(h2[6],h2[7])+b1p3, 1);
            F3 = lnact(mk2(h3[0],h3[1])+b1p0, mk2(h3[2],h3[3])+b1p1,
                       mk2(h3[4],h3[5])+b1p2, mk2(h3[6],h3[7])+b1p3, 1);

            // ---- layer 2 ----
            h0 = __builtin_amdgcn_mfma_f32_32x32x16_f16(aW2.v, F0.v, zC, 0,0,0);
            h1 = __builtin_amdgcn_mfma_f32_32x32x16_f16(aW2.v, F1.v, zC, 0,0,0);
            h2 = __builtin_amdgcn_mfma_f32_32x32x16_f16(aW2.v, F2.v, zC, 0,0,0);
            h3 = __builtin_amdgcn_mfma_f32_32x32x16_f16(aW2.v, F3.v, zC, 0,0,0);
            F0 = lnact(mk2(h0[0],h0[1])+b2p0, mk2(h0[2],h0[3])+b2p1,
                       mk2(h0[4],h0[5])+b2p2, mk2(h0[6],h0[7])+b2p3, 2);
            F1 = lnact(mk2(h1[0],h1[1])+b2p0, mk2(h1[2],h1[3])+b2p1,
                       mk2(h1[4],h1[5])+b2p2, mk2(h1[6],h1[7])+b2p3, 2);
            F2 = lnact(mk2(h2[0],h2[1])+b2p0, mk2(h2[2],h2[3])+b2p1,
                       mk2(h2[4],h2[5])+b2p2, mk2(h2[6],h2[7])+b2p3, 2);
            F3 = lnact(mk2(h3[0],h3[1])+b2p0, mk2(h3[2],h3[3])+b2p1,
                       mk2(h3[4],h3[5])+b2p2, mk2(h3[6],h3[7])+b2p3, 2);

            // ---- output layer (split: gg0 -> e0,e1 ; gg1 -> e2,e3) ----
            h0 = __builtin_amdgcn_mfma_f32_32x32x16_f16(aWo.v, F0.v, zC, 0,0,0);
            h1 = __builtin_amdgcn_mfma_f32_32x32x16_f16(aWo.v, F1.v, zC, 0,0,0);
            h2 = __builtin_amdgcn_mfma_f32_32x32x16_f16(aWo.v, F2.v, zC, 0,0,0);
            h3 = __builtin_amdgcn_mfma_f32_32x32x16_f16(aWo.v, F3.v, zC, 0,0,0);

            // f_a = 2 - 2/(exp(z*K + bo*K)+1), packed pre-scale then scalar trans
            f32x2 z0 = __builtin_elementwise_fma(mk2(h0[0],h0[1]), K2, bo22);
            f32x2 z1 = __builtin_elementwise_fma(mk2(h1[0],h1[1]), K2, bo22);
            f32x2 z2 = __builtin_elementwise_fma(mk2(h2[0],h2[1]), K2, bo22);
            f32x2 z3 = __builtin_elementwise_fma(mk2(h3[0],h3[1]), K2, bo22);
            float2 r0, r1, r2, r3;
            r0.x = fmaf(-2.0f, rcp_(ex2(z0.x)+1.0f), 2.0f);
            r0.y = fmaf(-2.0f, rcp_(ex2(z0.y)+1.0f), 2.0f);
            r1.x = fmaf(-2.0f, rcp_(ex2(z1.x)+1.0f), 2.0f);
            r1.y = fmaf(-2.0f, rcp_(ex2(z1.y)+1.0f), 2.0f);
            r2.x = fmaf(-2.0f, rcp_(ex2(z2.x)+1.0f), 2.0f);
            r2.y = fmaf(-2.0f, rcp_(ex2(z2.y)+1.0f), 2.0f);
            r3.x = fmaf(-2.0f, rcp_(ex2(z3.x)+1.0f), 2.0f);
            r3.y = fmaf(-2.0f, rcp_(ex2(z3.y)+1.0f), 2.0f);
            *(float2*)(ob + q*2048L       ) = r0;
            *(float2*)(ob + q*2048L +  512) = r1;
            *(float2*)(ob + q*2048L + 1024) = r2;
            *(float2*)(ob + q*2048L + 1536) = r3;
        }
    };

    if (triv) body(std::integral_constant<bool,true>{});
    else      body(std::integral_constant<bool,false>{});
}

extern "C" void kernel_launch(void* const* d_in, const int* in_sizes, int n_in,
                              void* d_out, int out_size, void* d_ws, size_t ws_size,
                              hipStream_t stream) {
    const float* feat = (const float*)d_in[0];
    const float* W0  = (const float*)d_in[1];
    const float* b0  = (const float*)d_in[2];
    const float* g0  = (const float*)d_in[3];
    const float* be0 = (const float*)d_in[4];
    const float* W1  = (const float*)d_in[5];
    const float* b1  = (const float*)d_in[6];
    const float* g1  = (const float*)d_in[7];
    const float* be1 = (const float*)d_in[8];
    const float* W2  = (const float*)d_in[9];
    const float* b2  = (const float*)d_in[10];
    const float* g2  = (const float*)d_in[11];
    const float* be2 = (const float*)d_in[12];
    const float* Wo  = (const float*)d_in[13];
    const float* bo  = (const float*)d_in[14];
    float* out = (float*)d_out;

    hipLaunchKernelGGL(nn_kernel, dim3(NBLOCKS), dim3(BLOCK), 0, stream,
                       feat, W0, b0, g0, be0, W1, b1, g1, be1,
                       W2, b2, g2, be2, Wo, bo, out);
}

// Round 19
// 72.385 us; speedup vs baseline: 1.0915x; 1.0161x over previous
//
#include <hip/hip_runtime.h>
#include <type_traits>

#define BLOCK 256
#define WAVES_PER_BLOCK 4
#define NBLOCKS 1024
#define TILES_PER_WAVE 32
#define QUADS (TILES_PER_WAVE/4)

typedef __fp16 f16;
typedef f16 f16x2 __attribute__((ext_vector_type(2)));
typedef f16 f16x8 __attribute__((ext_vector_type(8)));
typedef float f32x2 __attribute__((ext_vector_type(2)));
typedef float f32x16 __attribute__((ext_vector_type(16)));
typedef unsigned u32x2 __attribute__((ext_vector_type(2)));

__device__ __forceinline__ float ex2(float x){ return __builtin_amdgcn_exp2f(x); }
__device__ __forceinline__ float rcp_(float x){ return __builtin_amdgcn_rcpf(x); }
__device__ __forceinline__ float rsq_(float x){ return __builtin_amdgcn_rsqf(x); }

__device__ __forceinline__ f32x2 mk2(float a, float b){
    f32x2 r; r.x = a; r.y = b; return r;
}

__device__ __forceinline__ unsigned pk2(float a, float b){
    f16x2 h = __builtin_amdgcn_cvt_pkrtz(a, b);
    union { f16x2 h; unsigned u; } cv; cv.h = h; return cv.u;
}

// v_permlane32_swap_b32: r.x = {a_lo31, b_lo31}, r.y = {a_hi31, b_hi31}
__device__ __forceinline__ u32x2 plswap(unsigned a, unsigned b){
    return __builtin_amdgcn_permlane32_swap(a, b, false, false);
}
__device__ __forceinline__ float xhalf_sum(float x){
    union { float f; unsigned u; } cvt; cvt.f = x;
    u32x2 r = plswap(cvt.u, cvt.u);
    union { unsigned u; float f; } lo, hi; lo.u = r.x; hi.u = r.y;
    return lo.f + hi.f;
}

// exact-GELU via A&S 7.1.26 erf (|eps| <= 1.5e-7) — table build only
__device__ __forceinline__ float gelu_ref(float v){
    float av = fabsf(v);
    float e  = ex2(v*v * -0.7213475204444817f);
    float t  = rcp_(fmaf(0.23164190157f, av, 1.0f));
    float p  = fmaf(fmaf(fmaf(fmaf(1.061405429f, t, -1.453152027f), t,
                              1.421413741f), t, -0.284496736f), t, 0.254829592f);
    float pt = p * t;
    float erfabs = fmaf(-pt, e, 1.0f);
    return 0.5f * fmaf(av, erfabs, v);
}

union U8 { f16x8 v; unsigned u[4]; };
union PU { f16x2 v; unsigned u; };

__global__ __launch_bounds__(BLOCK) void nn_kernel(
    const float* __restrict__ feat,
    const float* __restrict__ W0, const float* __restrict__ b0v,
    const float* __restrict__ g0v, const float* __restrict__ be0v,
    const float* __restrict__ W1, const float* __restrict__ b1v,
    const float* __restrict__ g1v, const float* __restrict__ be1v,
    const float* __restrict__ W2, const float* __restrict__ b2v,
    const float* __restrict__ g2v, const float* __restrict__ be2v,
    const float* __restrict__ Wo, const float* __restrict__ bov,
    float* __restrict__ out)
{
    __shared__ __align__(16) f16   tabH[1024];   // f16 GELU table, step 1/128 (2KB)
    __shared__ __align__(16) float cb[3][16];
    __shared__ __align__(16) float cg[3][16];
    __shared__ __align__(16) float cbe[3][16];
    __shared__ __align__(16) float cbo[4];

    const int tid = threadIdx.x;
    if (tid < 16){
        cb[0][tid]  = b0v[tid];  cb[1][tid]  = b1v[tid];  cb[2][tid]  = b2v[tid];
        cg[0][tid]  = g0v[tid];  cg[1][tid]  = g1v[tid];  cg[2][tid]  = g2v[tid];
        cbe[0][tid] = be0v[tid]; cbe[1][tid] = be1v[tid]; cbe[2][tid] = be2v[tid];
    }
    if (tid < 4) cbo[tid] = bov[tid];
    for (int i = tid; i < 1024; i += BLOCK){
        float v = (float)(i - 512) * (1.0f/128.0f) + (0.5f/128.0f);
        tabH[i] = (f16)gelu_ref(v);
    }
    __syncthreads();

    const int lane = tid & 63;
    const int wv   = tid >> 6;
    const int gg   = lane >> 5;      // k-group / n-group selector
    const int c    = lane & 31;      // A row (neuron) / B col (data row)

    // ---- weight A-fragments: A[n][k] = W[k][n], lane: a[j]=A[c][gg*8+j] ----
    // layer-0: bias folded into k=8 (gg==1, j==0): A[n][8] = b0[n]; k=9..15 = 0
    U8 aW0, aW1, aW2, aWo;
    {
        float w[8];
        #pragma unroll
        for (int j=0;j<8;++j){
            if (gg==0) w[j] = (c<16) ? W0[j*16 + c] : 0.f;
            else       w[j] = (j==0 && c<16) ? b0v[c] : 0.f;
        }
        aW0.u[0]=pk2(w[0],w[1]); aW0.u[1]=pk2(w[2],w[3]);
        aW0.u[2]=pk2(w[4],w[5]); aW0.u[3]=pk2(w[6],w[7]);
        #pragma unroll
        for (int j=0;j<8;++j) w[j] = (c<16) ? W1[(gg*8+j)*16 + c] : 0.f;
        aW1.u[0]=pk2(w[0],w[1]); aW1.u[1]=pk2(w[2],w[3]);
        aW1.u[2]=pk2(w[4],w[5]); aW1.u[3]=pk2(w[6],w[7]);
        #pragma unroll
        for (int j=0;j<8;++j) w[j] = (c<16) ? W2[(gg*8+j)*16 + c] : 0.f;
        aW2.u[0]=pk2(w[0],w[1]); aW2.u[1]=pk2(w[2],w[3]);
        aW2.u[2]=pk2(w[4],w[5]); aW2.u[3]=pk2(w[6],w[7]);
        // output split: A rows 0,1 <- Wo cols 0,1 ; A rows 4,5 <- Wo cols 2,3
        const int eidx = (c < 2) ? c : ((c == 4 || c == 5) ? (c - 2) : -1);
        #pragma unroll
        for (int j=0;j<8;++j) w[j] = (eidx >= 0) ? Wo[(gg*8+j)*4 + eidx] : 0.f;
        aWo.u[0]=pk2(w[0],w[1]); aWo.u[1]=pk2(w[2],w[3]);
        aWo.u[2]=pk2(w[4],w[5]); aWo.u[3]=pk2(w[6],w[7]);
    }

    // ---- wave-uniform "gamma==1 && beta==0" fast-path flag ----
    bool okl = true;
    if (lane < 16){
        #pragma unroll
        for (int l=0;l<3;++l)
            okl = okl && (cg[l][lane]==1.0f) && (cbe[l][lane]==0.0f);
    }
    const bool triv = (__ballot(okl) == 0xFFFFFFFFFFFFFFFFull);

    // ---- per-lane bias pairs for layers 1,2 (packed f32) ----
    const int n0 = 4*gg, n1 = 8 + 4*gg;
    const float4 b1q0 = *(const float4*)&cb[1][n0], b1q1 = *(const float4*)&cb[1][n1];
    const float4 b2q0 = *(const float4*)&cb[2][n0], b2q1 = *(const float4*)&cb[2][n1];
    const f32x2 b1p0 = mk2(b1q0.x,b1q0.y), b1p1 = mk2(b1q0.z,b1q0.w);
    const f32x2 b1p2 = mk2(b1q1.x,b1q1.y), b1p3 = mk2(b1q1.z,b1q1.w);
    const f32x2 b2p0 = mk2(b2q0.x,b2q0.y), b2p1 = mk2(b2q0.z,b2q0.w);
    const f32x2 b2p2 = mk2(b2q1.x,b2q1.y), b2p3 = mk2(b2q1.z,b2q1.w);
    const float K = 2.8853900817779268f;   // 2/ln2
    const f32x2 K2   = mk2(K, K);
    const f32x2 bo22 = mk2(cbo[2*gg]*K, cbo[2*gg+1]*K);

    f32x16 zC;
    #pragma unroll
    for (int i=0;i<16;++i) zC[i]=0.f;

    const long gw = (long)blockIdx.x * WAVES_PER_BLOCK + wv;
    const long rowbase = gw * (TILES_PER_WAVE*32L);
    const char* fb = (const char*)feat + (rowbase + c) * 32L;   // same addr both halves
    char*       ob = (char*)out        + (rowbase + c) * 16L + gg*8;

    auto body = [&](auto TRIVC){
        constexpr bool TRIV = decltype(TRIVC)::value;

        // LN + GELU(f16 table) + pack -> next-layer B fragment
        auto lnact = [&](f32x2 h01, f32x2 h23, f32x2 h45, f32x2 h67, int l) -> U8 {
            f32x2 sp = (h01 + h23) + (h45 + h67);              // 3 pk_add
            float s  = sp.x + sp.y;
            f32x2 q  = h01 * h01;                              // pk_mul
            q = __builtin_elementwise_fma(h23, h23, q);        // pk_fma
            q = __builtin_elementwise_fma(h45, h45, q);
            q = __builtin_elementwise_fma(h67, h67, q);
            float s2 = q.x + q.y;
            s  = xhalf_sum(s);
            s2 = xhalf_sum(s2);
            const float mu  = s * 0.0625f;
            const float var = fmaf(-mu, mu, s2 * 0.0625f);
            const float rs  = rsq_(var + 1e-5f);

            PU p0, p1, p2, p3;
            if constexpr (TRIV){
                const float Ri = rs * 128.f;
                const float Ni = fmaf(-mu, Ri, 512.f);
                const f32x2 R2 = mk2(Ri, Ri), N2 = mk2(Ni, Ni);
                f32x2 i01 = __builtin_elementwise_fma(h01, R2, N2);
                f32x2 i23 = __builtin_elementwise_fma(h23, R2, N2);
                f32x2 i45 = __builtin_elementwise_fma(h45, R2, N2);
                f32x2 i67 = __builtin_elementwise_fma(h67, R2, N2);
                // idx guaranteed in [16, 1008]
                p0.v.x = tabH[(int)i01.x]; p0.v.y = tabH[(int)i01.y];
                p1.v.x = tabH[(int)i23.x]; p1.v.y = tabH[(int)i23.y];
                p2.v.x = tabH[(int)i45.x]; p2.v.y = tabH[(int)i45.y];
                p3.v.x = tabH[(int)i67.x]; p3.v.y = tabH[(int)i67.y];
            } else {
                const float nm = -mu * rs;
                const float4 gq0 = *(const float4*)&cg[l][n0];
                const float4 gq1 = *(const float4*)&cg[l][n1];
                const float4 eq0 = *(const float4*)&cbe[l][n0];
                const float4 eq1 = *(const float4*)&cbe[l][n1];
                const float hv[8] = {h01.x,h01.y,h23.x,h23.y,h45.x,h45.y,h67.x,h67.y};
                const float ga[8] = {gq0.x,gq0.y,gq0.z,gq0.w, gq1.x,gq1.y,gq1.z,gq1.w};
                const float ba[8] = {eq0.x,eq0.y,eq0.z,eq0.w, eq1.x,eq1.y,eq1.z,eq1.w};
                float xf[8];
                #pragma unroll
                for (int i=0;i<8;++i){
                    float t  = fmaf(hv[i], rs, nm);
                    t = fmaf(t, ga[i], ba[i]);
                    xf[i] = fminf(fmaxf(fmaf(t, 128.f, 512.f), 0.f), 1023.f);
                }
                p0.v.x = tabH[(int)xf[0]]; p0.v.y = tabH[(int)xf[1]];
                p1.v.x = tabH[(int)xf[2]]; p1.v.y = tabH[(int)xf[3]];
                p2.v.x = tabH[(int)xf[4]]; p2.v.y = tabH[(int)xf[5]];
                p3.v.x = tabH[(int)xf[6]]; p3.v.y = tabH[(int)xf[7]];
            }
            u32x2 e0 = plswap(p0.u, p2.u);
            u32x2 e1 = plswap(p1.u, p3.u);
            U8 F;
            F.u[0] = e0.x; F.u[1] = e1.x; F.u[2] = e0.y; F.u[3] = e1.y;
            return F;
        };

        // ---- prefetch tiles 0,1 of quad 0 ----
        float4 p0a = *(const float4*)(fb +    0), p0b = *(const float4*)(fb +   16);
        float4 p1a = *(const float4*)(fb + 1024), p1b = *(const float4*)(fb + 1040);

        #pragma unroll 1
        for (int q = 0; q < QUADS; ++q){
            const char* fq = fb + q*4096L;

            // ---- tiles 2,3 of this quad load now ----
            float4 t2a = *(const float4*)(fq + 2048), t2b = *(const float4*)(fq + 2064);
            float4 t3a = *(const float4*)(fq + 3072), t3b = *(const float4*)(fq + 3088);

            // ---- layer-0 B fragments (tiles 0,1 from prefetch regs) ----
            U8 B0, B1, B2, B3;
            B0.u[0]=pk2(p0a.x,p0a.y); B0.u[1]=pk2(p0a.z,p0a.w);
            B0.u[2]=pk2(p0b.x,p0b.y); B0.u[3]=pk2(p0b.z,p0b.w);
            B1.u[0]=pk2(p1a.x,p1a.y); B1.u[1]=pk2(p1a.z,p1a.w);
            B1.u[2]=pk2(p1b.x,p1b.y); B1.u[3]=pk2(p1b.z,p1b.w);
            B2.u[0]=pk2(t2a.x,t2a.y); B2.u[1]=pk2(t2a.z,t2a.w);
            B2.u[2]=pk2(t2b.x,t2b.y); B2.u[3]=pk2(t2b.z,t2b.w);
            B3.u[0]=pk2(t3a.x,t3a.y); B3.u[1]=pk2(t3a.z,t3a.w);
            B3.u[2]=pk2(t3b.x,t3b.y); B3.u[3]=pk2(t3b.z,t3b.w);
            if (gg){
                B0.u[0]=0x00003C00u; B1.u[0]=0x00003C00u;
                B2.u[0]=0x00003C00u; B3.u[0]=0x00003C00u;
            }

            // ---- issue next quad's tiles 0,1 now (hide HBM under compute) ----
            {
                const char* pn = fb + ((q+1 < QUADS) ? (q+1) : q)*4096L;
                p0a = *(const float4*)(pn +    0); p0b = *(const float4*)(pn +   16);
                p1a = *(const float4*)(pn + 1024); p1b = *(const float4*)(pn + 1040);
            }

            // ---- layer 0 ----
            f32x16 h0 = __builtin_amdgcn_mfma_f32_32x32x16_f16(aW0.v, B0.v, zC, 0,0,0);
            f32x16 h1 = __builtin_amdgcn_mfma_f32_32x32x16_f16(aW0.v, B1.v, zC, 0,0,0);
            f32x16 h2 = __builtin_amdgcn_mfma_f32_32x32x16_f16(aW0.v, B2.v, zC, 0,0,0);
            f32x16 h3 = __builtin_amdgcn_mfma_f32_32x32x16_f16(aW0.v, B3.v, zC, 0,0,0);

            U8 F0 = lnact(mk2(h0[0],h0[1]), mk2(h0[2],h0[3]), mk2(h0[4],h0[5]), mk2(h0[6],h0[7]), 0);
            U8 F1 = lnact(mk2(h1[0],h1[1]), mk2(h1[2],h1[3]), mk2(h1[4],h1[5]), mk2(h1[6],h1[7]), 0);
            U8 F2 = lnact(mk2(h2[0],h2[1]), mk2(h2[2],h2[3]), mk2(h2[4],h2[5]), mk2(h2[6],h2[7]), 0);
            U8 F3 = lnact(mk2(h3[0],h3[1]), mk2(h3[2],h3[3]), mk2(h3[4],h3[5]), mk2(h3[6],h3[7]), 0);

            // ---- layer 1 (bias added packed) ----
            h0 = __builtin_amdgcn_mfma_f32_32x32x16_f16(aW1.v, F0.v, zC, 0,0,0);
            h1 = __builtin_amdgcn_mfma_f32_32x32x16_f16(aW1.v, F1.v, zC, 0,0,0);
            h2 = __builtin_amdgcn_mfma_f32_32x32x16_f16(aW1.v, F2.v, zC, 0,0,0);
            h3 = __builtin_amdgcn_mfma_f32_32x32x16_f16(aW1.v, F3.v, zC, 0,0,0);
            F0 = lnact(mk2(h0[0],h0[1])+b1p0, mk2(h0[2],h0[3])+b1p1,
                       mk2(h0[4],h0[5])+b1p2, mk2(h0[6],h0[7])+b1p3, 1);
            F1 = lnact(mk2(h1[0],h1[1])+b1p0, mk2(h1[2],h1[3])+b1p1,
                       mk2(h1[4],h1[5])+b1p2, mk2(h1[6],h1[7])+b1p3, 1);
            F2 = lnact(mk2(h2[0],h2[1])+b1p0, mk2(h2[2],h2[3])+b1p1,
                       mk2(h2[4],h2[5])+b1p2, mk2(h2[6],h2[7])+b1p3, 1);
            F3 = lnact(mk2(h3[0],h3[1])+b1p0, mk2(h3[2],h3[3])+b1p1,
                       mk2(h3[4],h3[5])+b1p2, mk2(h3[6],h3[7])+b1p3, 1);

            // ---- layer 2 ----
            h0 = __builtin_amdgcn_mfma_f32_32x32x16_f16(aW2.v, F0.v, zC, 0,0,0);
            h1 = __builtin_amdgcn_mfma_f32_32x32x16_f16(aW2.v, F1.v, zC, 0,0,0);
            h2 = __builtin_amdgcn_mfma_f32_32x32x16_f16(aW2.v, F2.v, zC, 0,0,0);
            h3 = __builtin_amdgcn_mfma_f32_32x32x16_f16(aW2.v, F3.v, zC, 0,0,0);
            F0 = lnact(mk2(h0[0],h0[1])+b2p0, mk2(h0[2],h0[3])+b2p1,
                       mk2(h0[4],h0[5])+b2p2, mk2(h0[6],h0[7])+b2p3, 2);
            F1 = lnact(mk2(h1[0],h1[1])+b2p0, mk2(h1[2],h1[3])+b2p1,
                       mk2(h1[4],h1[5])+b2p2, mk2(h1[6],h1[7])+b2p3, 2);
            F2 = lnact(mk2(h2[0],h2[1])+b2p0, mk2(h2[2],h2[3])+b2p1,
                       mk2(h2[4],h2[5])+b2p2, mk2(h2[6],h2[7])+b2p3, 2);
            F3 = lnact(mk2(h3[0],h3[1])+b2p0, mk2(h3[2],h3[3])+b2p1,
                       mk2(h3[4],h3[5])+b2p2, mk2(h3[6],h3[7])+b2p3, 2);

            // ---- output layer (split: gg0 -> e0,e1 ; gg1 -> e2,e3) ----
            h0 = __builtin_amdgcn_mfma_f32_32x32x16_f16(aWo.v, F0.v, zC, 0,0,0);
            h1 = __builtin_amdgcn_mfma_f32_32x32x16_f16(aWo.v, F1.v, zC, 0,0,0);
            h2 = __builtin_amdgcn_mfma_f32_32x32x16_f16(aWo.v, F2.v, zC, 0,0,0);
            h3 = __builtin_amdgcn_mfma_f32_32x32x16_f16(aWo.v, F3.v, zC, 0,0,0);

            // f_a = 2 - 2/(exp(z*K + bo*K)+1), packed pre-scale then scalar trans
            f32x2 z0 = __builtin_elementwise_fma(mk2(h0[0],h0[1]), K2, bo22);
            f32x2 z1 = __builtin_elementwise_fma(mk2(h1[0],h1[1]), K2, bo22);
            f32x2 z2 = __builtin_elementwise_fma(mk2(h2[0],h2[1]), K2, bo22);
            f32x2 z3 = __builtin_elementwise_fma(mk2(h3[0],h3[1]), K2, bo22);
            float2 r0, r1, r2, r3;
            r0.x = fmaf(-2.0f, rcp_(ex2(z0.x)+1.0f), 2.0f);
            r0.y = fmaf(-2.0f, rcp_(ex2(z0.y)+1.0f), 2.0f);
            r1.x = fmaf(-2.0f, rcp_(ex2(z1.x)+1.0f), 2.0f);
            r1.y = fmaf(-2.0f, rcp_(ex2(z1.y)+1.0f), 2.0f);
            r2.x = fmaf(-2.0f, rcp_(ex2(z2.x)+1.0f), 2.0f);
            r2.y = fmaf(-2.0f, rcp_(ex2(z2.y)+1.0f), 2.0f);
            r3.x = fmaf(-2.0f, rcp_(ex2(z3.x)+1.0f), 2.0f);
            r3.y = fmaf(-2.0f, rcp_(ex2(z3.y)+1.0f), 2.0f);
            *(float2*)(ob + q*2048L       ) = r0;
            *(float2*)(ob + q*2048L +  512) = r1;
            *(float2*)(ob + q*2048L + 1024) = r2;
            *(float2*)(ob + q*2048L + 1536) = r3;
        }
    };

    if (triv) body(std::integral_constant<bool,true>{});
    else      body(std::integral_constant<bool,false>{});
}

extern "C" void kernel_launch(void* const* d_in, const int* in_sizes, int n_in,
                              void* d_out, int out_size, void* d_ws, size_t ws_size,
                              hipStream_t stream) {
    const float* feat = (const float*)d_in[0];
    const float* W0  = (const float*)d_in[1];
    const float* b0  = (const float*)d_in[2];
    const float* g0  = (const float*)d_in[3];
    const float* be0 = (const float*)d_in[4];
    const float* W1  = (const float*)d_in[5];
    const float* b1  = (const float*)d_in[6];
    const float* g1  = (const float*)d_in[7];
    const float* be1 = (const float*)d_in[8];
    const float* W2  = (const float*)d_in[9];
    const float* b2  = (const float*)d_in[10];
    const float* g2  = (const float*)d_in[11];
    const float* be2 = (const float*)d_in[12];
    const float* Wo  = (const float*)d_in[13];
    const float* bo  = (const float*)d_in[14];
    float* out = (float*)d_out;

    hipLaunchKernelGGL(nn_kernel, dim3(NBLOCKS), dim3(BLOCK), 0, stream,
                       feat, W0, b0, g0, be0, W1, b1, g1, be1,
                       W2, b2, g2, be2, Wo, bo, out);
}